// Round 1
// baseline (697.796 us; speedup 1.0000x reference)
//
#include <hip/hip_runtime.h>
#include <hip/hip_bf16.h>

// Problem constants (fixed by reference)
#define NCH   4096   // children
#define NPAR  128    // parents
#define KD    16
#define CHUNK 128                 // children per block in pool_pairs
#define NCHUNK (NCH / CHUNK)      // 32
#define PITCH 24                  // ushorts per LDS matrix row (48 B, 16B-aligned, ~2-way banks = free)

typedef __attribute__((ext_vector_type(4))) float f4;
typedef __attribute__((ext_vector_type(8))) short bh8;
typedef __attribute__((ext_vector_type(4))) int   i4;
typedef __attribute__((ext_vector_type(2))) unsigned int u2;

static __device__ __forceinline__ unsigned pk2(float a, float b) {
  float2 t; t.x = a; t.y = b;
  union { __hip_bfloat162 h2; unsigned u; } cv;
  cv.h2 = __float22bfloat162_rn(t);   // .x in low 16 bits
  return cv.u;
}
static __device__ __forceinline__ float bflo(unsigned v) { return __uint_as_float(v << 16); }
static __device__ __forceinline__ float bfhi(unsigned v) { return __uint_as_float(v & 0xFFFF0000u); }

// ---------------------------------------------------------------------------
// Phase 1: Lambda_n = inv(Sigma_n), 16x16 SPD Gauss-Jordan (no pivoting; diag>=1).
// Output stored as bf16 (halves L2 traffic in phase 2; precision ample).
// ---------------------------------------------------------------------------
__global__ __launch_bounds__(256) void invert_sigma(const float* __restrict__ sig,
                                                    unsigned short* __restrict__ lam) {
  __shared__ float A[16][17];
  __shared__ float B[16][17];
  const int n = blockIdx.x;
  const int t = threadIdx.x, i = t >> 4, j = t & 15;
  A[i][j] = sig[(size_t)n * 256 + t];
  B[i][j] = (i == j) ? 1.0f : 0.0f;
  __syncthreads();
  for (int k = 0; k < 16; ++k) {
    const float ip  = 1.0f / A[k][k];
    const float akj = A[k][j] * ip;
    const float bkj = B[k][j] * ip;
    const float f   = A[i][k];
    __syncthreads();
    if (i == k) { A[i][j] = akj;      B[i][j] = bkj; }
    else        { A[i][j] -= f * akj; B[i][j] -= f * bkj; }
    __syncthreads();
  }
  __hip_bfloat16 h = __float2bfloat16(B[i][j]);
  lam[(size_t)n * 256 + t] = *reinterpret_cast<unsigned short*>(&h);
}

// ---------------------------------------------------------------------------
// Phase 2: per pair (m,n):  Ct = Omega Lambda Omega^T  via 2 bf16 MFMAs.
//   One fragment F (lane holds row t=lane&15, cols q*8..q*8+7, q=lane>>4, quads>=2 zero)
//   acts as A == Omega and as B == Omega^T.
//   MFMA1: P = A(Lambda) * B(Omega^T).  C-layout of P (row=q*4+r, col=t) is repacked
//   to B-layout ([P;0], 32x16) with 4 shuffles after per-lane bf16 cvt.
//   MFMA2: Ct = A(Omega) * B(P) = Omega Lambda Omega^T.
//   mu_t[t] = dot(Omega row t, mu) from the register fragment + xor-shuffle over quads.
//   accLp[r]  += w * Ct[r];  accInfo[r] += (w*mu_t[t]) * Ct[r].
// Wave-private LDS buffers -> no __syncthreads in the hot loop (no vmcnt(0) barrier drain).
// ---------------------------------------------------------------------------
__global__ __launch_bounds__(256) void pool_pairs(
    const float* __restrict__ transport,
    const unsigned short* __restrict__ lam,
    const float* __restrict__ mu,
    const float* __restrict__ weights,
    float* __restrict__ Lp,     // (128,16,16) accumulated via atomics (pre-zeroed)
    float* __restrict__ info) { // (128,16)
  __shared__ unsigned short sOm[4][16 * PITCH];
  __shared__ unsigned short sLm[4][16 * PITCH];
  __shared__ float sMu[CHUNK * 16];
  __shared__ float sW[CHUNK];
  __shared__ float sRedLp[4][256];
  __shared__ float sRedIn[4][16];

  const int bx = blockIdx.x;
  const int m  = bx & (NPAR - 1);     // consecutive blocks share the n-chunk -> L2 reuse of Lambda/mu
  const int c  = bx >> 7;
  const int tid = threadIdx.x;
  const int w = tid >> 6;             // wave id
  const int L = tid & 63;             // lane
  const int q = L >> 4;               // quad
  const int t = L & 15;

  // Prestage chunk mu (CHUNK*16 f32) and weights column for this m.
  #pragma unroll
  for (int r = 0; r < (CHUNK * 16) / 256; ++r) {
    const int idx = r * 256 + tid;
    sMu[idx] = mu[(size_t)c * CHUNK * 16 + idx];
  }
  if (tid < CHUNK) sW[tid] = weights[(size_t)(c * CHUNK + tid) * NPAR + m];
  __syncthreads();

  const int PER_WAVE = CHUNK / 4;                 // 32 pairs per wave
  const int n0 = c * CHUNK + w * PER_WAVE;        // global child base for this wave
  unsigned short* om = sOm[w];
  unsigned short* lm = sLm[w];

  const int wr_off = (L >> 2) * PITCH + (L & 3) * 4;  // staging write (4 bf16 per lane)
  const int rd_off = t * PITCH + q * 8;               // fragment read (8 bf16, q<2)

  f4 accLp = {0.f, 0.f, 0.f, 0.f};
  f4 accIn = {0.f, 0.f, 0.f, 0.f};
  const f4 zf = {0.f, 0.f, 0.f, 0.f};

  const float* tbase = transport + ((size_t)m * NCH + n0) * 256;
  const unsigned short* lbase = lam + (size_t)n0 * 256;

  // 1-deep register prefetch (16 waves/CU * 1.5KB in flight covers ~900cy HBM latency)
  f4 omNext = *(const f4*)(tbase + 4 * L);
  u2 lmNext = *(const u2*)(lbase + 4 * L);

  for (int it = 0; it < PER_WAVE; ++it) {
    const f4 omv = omNext;
    const u2 lmv = lmNext;
    const int itn = (it + 1 < PER_WAVE) ? it + 1 : it;
    omNext = *(const f4*)(tbase + (size_t)itn * 256 + 4 * L);
    lmNext = *(const u2*)(lbase + (size_t)itn * 256 + 4 * L);
    const int nloc = w * PER_WAVE + it;

    // Stage Omega (cvt f32->bf16) and Lambda (already bf16) into wave-private LDS
    u2 omp; omp.x = pk2(omv.x, omv.y); omp.y = pk2(omv.z, omv.w);
    *(u2*)(om + wr_off) = omp;
    *(u2*)(lm + wr_off) = lmv;
    __builtin_amdgcn_wave_barrier();   // compiler fence; DS ops are in-order per wave

    i4 aOmI = {0, 0, 0, 0}, aLmI = {0, 0, 0, 0};
    if (q < 2) {
      aOmI = *(const i4*)(om + rd_off);
      aLmI = *(const i4*)(lm + rd_off);
    }
    union { i4 i; bh8 h; } cvo, cvl, cvp;
    cvo.i = aOmI; cvl.i = aLmI;

    // mu_t[t] = sum_k Omega[t][k]*mu[k]: register dot + reduce over quads
    const float* muv = sMu + nloc * 16 + (q & 1) * 8;   // q>=2 reads garbage*0
    const f4 mlo = *(const f4*)(muv);
    const f4 mhi = *(const f4*)(muv + 4);
    const unsigned a0 = (unsigned)aOmI.x, a1 = (unsigned)aOmI.y,
                   a2 = (unsigned)aOmI.z, a3 = (unsigned)aOmI.w;
    float p = bflo(a0) * mlo.x + bfhi(a0) * mlo.y + bflo(a1) * mlo.z + bfhi(a1) * mlo.w +
              bflo(a2) * mhi.x + bfhi(a2) * mhi.y + bflo(a3) * mhi.z + bfhi(a3) * mhi.w;
    p += __shfl_xor(p, 16, 64);
    p += __shfl_xor(p, 32, 64);        // now p = mu_t[t] in every lane

    // MFMA1: P = Lambda * Omega^T   (A=Lambda frag, B=Omega frag => Omega^T)
    f4 P = __builtin_amdgcn_mfma_f32_16x16x32_bf16(cvl.h, cvo.h, zf, 0, 0, 0);

    // Repack P (C-layout) -> B-layout [P;0]: lane(q,t) needs P[q*8+j][t]
    const unsigned pkLoV = pk2(P.x, P.y);
    const unsigned pkHiV = pk2(P.z, P.w);
    const int srcA = t + (q & 1) * 32;
    int w0 = __shfl((int)pkLoV, srcA, 64);
    int w1 = __shfl((int)pkHiV, srcA, 64);
    int w2 = __shfl((int)pkLoV, srcA + 16, 64);
    int w3 = __shfl((int)pkHiV, srcA + 16, 64);
    i4 bPI;
    bPI.x = (q < 2) ? w0 : 0;
    bPI.y = (q < 2) ? w1 : 0;
    bPI.z = (q < 2) ? w2 : 0;
    bPI.w = (q < 2) ? w3 : 0;
    cvp.i = bPI;

    // MFMA2: Ct = Omega * P = Omega Lambda Omega^T
    f4 Ct = __builtin_amdgcn_mfma_f32_16x16x32_bf16(cvo.h, cvp.h, zf, 0, 0, 0);

    const float wv = sW[nloc];
    const float wmu = wv * p;
    accLp.x += wv * Ct.x;  accIn.x += wmu * Ct.x;
    accLp.y += wv * Ct.y;  accIn.y += wmu * Ct.y;
    accLp.z += wv * Ct.z;  accIn.z += wmu * Ct.z;
    accLp.w += wv * Ct.w;  accIn.w += wmu * Ct.w;
    __builtin_amdgcn_wave_barrier();   // keep this iter's reads ahead of next iter's writes
  }

  // Per-wave partials -> LDS
  sRedLp[w][(q * 4 + 0) * 16 + t] = accLp.x;
  sRedLp[w][(q * 4 + 1) * 16 + t] = accLp.y;
  sRedLp[w][(q * 4 + 2) * 16 + t] = accLp.z;
  sRedLp[w][(q * 4 + 3) * 16 + t] = accLp.w;

  float i0 = accIn.x, i1 = accIn.y, i2 = accIn.z, i3 = accIn.w;
  #pragma unroll
  for (int off = 1; off < 16; off <<= 1) {
    i0 += __shfl_xor(i0, off, 64);
    i1 += __shfl_xor(i1, off, 64);
    i2 += __shfl_xor(i2, off, 64);
    i3 += __shfl_xor(i3, off, 64);
  }
  if (t == 0) {
    sRedIn[w][q * 4 + 0] = i0;
    sRedIn[w][q * 4 + 1] = i1;
    sRedIn[w][q * 4 + 2] = i2;
    sRedIn[w][q * 4 + 3] = i3;
  }
  __syncthreads();

  const float s = sRedLp[0][tid] + sRedLp[1][tid] + sRedLp[2][tid] + sRedLp[3][tid];
  atomicAdd(&Lp[(size_t)m * 256 + tid], s);
  if (tid < 16) {
    const float si = sRedIn[0][tid] + sRedIn[1][tid] + sRedIn[2][tid] + sRedIn[3][tid];
    atomicAdd(&info[(size_t)m * 16 + tid], si);
  }
}

// ---------------------------------------------------------------------------
// Phase 3: symmetrize Lp, invert (eigenclamp at 1e-4 is a provable no-op:
// Lp eigenvalues are O(50..5000)), mu = Sigma_pooled * info.
// ---------------------------------------------------------------------------
__global__ __launch_bounds__(256) void finalize(const float* __restrict__ Lp,
                                                const float* __restrict__ info,
                                                float* __restrict__ out) {
  __shared__ float A[16][17];
  __shared__ float B[16][17];
  __shared__ float infoS[16];
  const int m = blockIdx.x;
  const int tid = threadIdx.x, i = tid >> 4, j = tid & 15;
  const float* Lm = Lp + (size_t)m * 256;
  A[i][j] = 0.5f * (Lm[i * 16 + j] + Lm[j * 16 + i]);
  B[i][j] = (i == j) ? 1.0f : 0.0f;
  if (tid < 16) infoS[tid] = info[(size_t)m * 16 + tid];
  __syncthreads();
  for (int k = 0; k < 16; ++k) {
    const float ip  = 1.0f / A[k][k];
    const float akj = A[k][j] * ip;
    const float bkj = B[k][j] * ip;
    const float f   = A[i][k];
    __syncthreads();
    if (i == k) { A[i][j] = akj;      B[i][j] = bkj; }
    else        { A[i][j] -= f * akj; B[i][j] -= f * bkj; }
    __syncthreads();
  }
  // sigma_pooled
  out[(size_t)KD * NPAR + (size_t)m * 256 + tid] = B[i][j];
  // mu_pooled
  if (tid < 16) {
    float s = 0.f;
    #pragma unroll
    for (int jj = 0; jj < 16; ++jj) s += B[tid][jj] * infoS[jj];
    out[(size_t)m * 16 + tid] = s;
  }
}

// ---------------------------------------------------------------------------
extern "C" void kernel_launch(void* const* d_in, const int* in_sizes, int n_in,
                              void* d_out, int out_size, void* d_ws, size_t ws_size,
                              hipStream_t stream) {
  const float* mu_children    = (const float*)d_in[0];  // (N,K)
  const float* sigma_children = (const float*)d_in[1];  // (N,K,K)
  const float* weights        = (const float*)d_in[2];  // (N,M)
  const float* transport      = (const float*)d_in[3];  // (M,N,K,K)
  float* out = (float*)d_out;                           // mu (M,K) ++ sigma (M,K,K)

  // ws layout: [0,2MB) Lambda bf16; then Lp f32 (128*256); then info f32 (128*16)
  unsigned short* lam = (unsigned short*)d_ws;
  float* Lp   = (float*)((char*)d_ws + (size_t)NCH * 256 * sizeof(unsigned short));
  float* info = Lp + (size_t)NPAR * 256;

  hipMemsetAsync(Lp, 0, (size_t)(NPAR * 256 + NPAR * 16) * sizeof(float), stream);
  invert_sigma<<<NCH, 256, 0, stream>>>(sigma_children, lam);
  pool_pairs<<<NPAR * NCHUNK, 256, 0, stream>>>(transport, lam, mu_children, weights, Lp, info);
  finalize<<<NPAR, 256, 0, stream>>>(Lp, info, out);
}